// Round 10
// baseline (480.136 us; speedup 1.0000x reference)
//
#include <hip/hip_runtime.h>
#include <hip/hip_bf16.h>
#include <stdint.h>

using f32x4  = __attribute__((ext_vector_type(4))) float;
using bf16x8 = __attribute__((ext_vector_type(8))) short;
using bf16x4 = __attribute__((ext_vector_type(4))) short;

#define NB   4
#define NC   128
#define NT   8192
#define TL   32
#define NLAYER 20
#define CONVN (NLAYER * 256 * 256)
#define WOUTN (NLAYER * 128 * 128)

__device__ __forceinline__ short f2b(float f) {
  union { float f; unsigned u; } v; v.f = f;
  unsigned r = v.u + 0x7FFFu + ((v.u >> 16) & 1u);   // RNE
  return (short)(r >> 16);
}

__device__ __forceinline__ float b2f(short s) {
  union { unsigned u; float f; } v;
  v.u = ((unsigned)(unsigned short)s) << 16;
  return v.f;
}

__device__ __forceinline__ f32x4 mfma16(bf16x8 a, bf16x8 b, f32x4 c) {
  return __builtin_amdgcn_mfma_f32_16x16x32_bf16(a, b, c, 0, 0, 0);
}

__device__ __forceinline__ void gl_lds16(const void* g, void* l) {
  __builtin_amdgcn_global_load_lds(
      (const __attribute__((address_space(1))) void*)g,
      (__attribute__((address_space(3))) void*)l, 16, 0, 0);
}

// x [NB][NC][NT] f32 -> xtb bf16 swizzled (256B rows, 16B groups XOR t&7)
__global__ void transpose_in(const float* __restrict__ x, short* __restrict__ xtb) {
  __shared__ float tile[64][65];
  const int t0 = blockIdx.x * 64;
  const int c0 = blockIdx.y * 64;
  const int b  = blockIdx.z;
  const int lane = threadIdx.x & 63;
  const int r4   = threadIdx.x >> 6;
  #pragma unroll
  for (int i = 0; i < 16; ++i) {
    const int cl = i * 4 + r4;
    tile[cl][lane] = x[((size_t)(b * NC + c0 + cl)) * NT + t0 + lane];
  }
  __syncthreads();
  #pragma unroll
  for (int it = 0; it < 2; ++it) {
    const int idx = it * 256 + threadIdx.x;
    const int r  = idx >> 3;
    const int gi = idx & 7;
    bf16x8 v;
    #pragma unroll
    for (int jj = 0; jj < 8; ++jj) v[jj] = f2b(tile[gi * 8 + jj][r]);
    const int t = t0 + r;
    const int ci = ((c0 >> 3) + gi) ^ (t & 7);
    *(bf16x8*)((char*)xtb + ((size_t)(b * NT + t)) * 256 + ci * 16) = v;
  }
}

// pack weights to bf16, fragment-ordered: wcb[l][o][k] with k = tap*128 + c
__global__ void pack_weights(const float* __restrict__ w_conv,
                             const float* __restrict__ w_out,
                             short* __restrict__ wcb, short* __restrict__ wob) {
  const int idx = blockIdx.x * 256 + threadIdx.x;
  if (idx < CONVN) {
    const int k = idx & 255, o = (idx >> 8) & 255, lyr = idx >> 16;
    const int tap = k >> 7, c = k & 127;
    wcb[idx] = f2b(w_conv[(((size_t)lyr * 256 + o) * 128 + c) * 2 + tap]);
  } else if (idx < CONVN + WOUTN) {
    const int j = idx - CONVN;
    wob[j] = f2b(w_out[j]);
  }
}

// One layer, TL=32 tiles, 1024 blocks, 8 waves. 3 barriers (2 on last layer).
__global__ __launch_bounds__(512, 4)
void wavenet_layer32(const short* __restrict__ wcb,
                     const float* __restrict__ b_conv,
                     const short* __restrict__ wob,
                     const float* __restrict__ b_out,
                     const short* __restrict__ xbin,
                     short* __restrict__ xbout,
                     float* __restrict__ out,
                     int layer, int dil, int last)
{
  __shared__ char ldsXC[TL * 256];   // 8 KB each
  __shared__ char ldsXP[TL * 256];
  __shared__ char ldsG [TL * 256];

  const int tid = threadIdx.x;
  const int w   = tid >> 6;
  const int l   = tid & 63;
  const int lh  = l & 15;
  const int lq  = l >> 4;
  const int o0  = 16 * w + lq * 4;
  // XCD swizzle: 1024 blocks -> 8 XCD chunks of 128 consecutive t-tiles
  const int uid = (blockIdx.x & 7) * 128 + (blockIdx.x >> 3);
  const int b   = uid >> 8;
  const int t0  = (uid & 255) * 32;

  // ---- stage XC / XP (8 KB each; 512 x 16 B) ----
  {
    const char* xcg = (const char*)xbin + ((size_t)(b * NT + t0)) * 256;
    gl_lds16(xcg + tid * 16, ldsXC + tid * 16);
  }
  if (t0 >= dil) {
    const char* xpg = (const char*)xbin + ((size_t)(b * NT + t0 - dil)) * 256;
    gl_lds16(xpg + tid * 16, ldsXP + tid * 16);
  } else {
    const int row = tid >> 4, p = tid & 15;
    const int tp = t0 + row - dil;
    char* dst = ldsXP + row * 256 + p * 16;
    if (tp >= 0) {
      const char* src = (const char*)xbin + ((size_t)(b * NT + tp)) * 256;
      *(bf16x8*)dst = *(const bf16x8*)(src + p * 16);
    } else {
      bf16x8 z = {0, 0, 0, 0, 0, 0, 0, 0};
      *(bf16x8*)dst = z;
    }
  }
  __syncthreads();

  // ---- GEMM1: z[256 x 32] ----
  const f32x4 fz = {0.f, 0.f, 0.f, 0.f};
  f32x4 acc1[2][2];
  #pragma unroll
  for (int mi = 0; mi < 2; ++mi)
    #pragma unroll
    for (int n = 0; n < 2; ++n) acc1[mi][n] = fz;

  const short* wl = wcb + (size_t)layer * 65536;
  #pragma unroll
  for (int ks = 0; ks < 8; ++ks) {
    const bf16x8 a0 = *(const bf16x8*)(wl + (16 * w + lh) * 256 + ks * 32 + lq * 8);
    const bf16x8 a1 = *(const bf16x8*)(wl + (128 + 16 * w + lh) * 256 + ks * 32 + lq * 8);
    const char* base = (ks < 4) ? ldsXP : ldsXC;
    const int dd = (ks < 4) ? dil : 0;
    #pragma unroll
    for (int n = 0; n < 2; ++n) {
      const int tt = n * 16 + lh;
      const int ci = ((ks & 3) * 4 + lq) ^ ((tt - dd) & 7);
      const bf16x8 bb = *(const bf16x8*)(base + tt * 256 + ci * 16);
      acc1[0][n] = mfma16(a0, bb, acc1[0][n]);
      acc1[1][n] = mfma16(a1, bb, acc1[1][n]);
    }
  }

  // ---- gate -> G (256B swizzled rows) ----
  {
    float ba[4], bs[4];
    #pragma unroll
    for (int r = 0; r < 4; ++r) {
      ba[r] = b_conv[layer * 256 + o0 + r];
      bs[r] = b_conv[layer * 256 + 128 + o0 + r];
    }
    #pragma unroll
    for (int n = 0; n < 2; ++n) {
      bf16x4 g4;
      #pragma unroll
      for (int r = 0; r < 4; ++r) {
        const float za = acc1[0][n][r] + ba[r];
        const float zb = acc1[1][n][r] + bs[r];
        const float th = 1.f - 2.f / (1.f + __expf(2.f * za));
        const float sg = 1.f / (1.f + __expf(-zb));
        g4[r] = f2b(th * sg);
      }
      const int tt = n * 16 + lh;
      const int ci = (o0 >> 3) ^ (tt & 7);
      *(bf16x4*)(ldsG + tt * 256 + ci * 16 + (o0 & 7) * 2) = g4;
    }
  }
  __syncthreads();

  // ---- GEMM2: s[128 x 32] ----
  f32x4 acc2[2];
  #pragma unroll
  for (int n = 0; n < 2; ++n) acc2[n] = fz;
  const short* wol = wob + (size_t)layer * 16384;
  #pragma unroll
  for (int ks = 0; ks < 4; ++ks) {
    const bf16x8 a = *(const bf16x8*)(wol + (16 * w + lh) * 128 + ks * 32 + lq * 8);
    #pragma unroll
    for (int n = 0; n < 2; ++n) {
      const int tt = n * 16 + lh;
      const int ci = (ks * 4 + lq) ^ (tt & 7);
      const bf16x8 bb = *(const bf16x8*)(ldsG + tt * 256 + ci * 16);
      acc2[n] = mfma16(a, bb, acc2[n]);
    }
  }

  // ---- epilogue: direct NT skip stores; xn -> XC in place (wave-private cols) ----
  const size_t XOFFS = (size_t)NB * NC * NT;
  {
    float bo[4];
    #pragma unroll
    for (int r = 0; r < 4; ++r) bo[r] = b_out[layer * 128 + o0 + r];
    float* skipBase = out + XOFFS + ((size_t)((layer * NB + b) * NC)) * NT + t0;
    float* xBase    = out + ((size_t)(b * NC)) * NT + t0;
    #pragma unroll
    for (int n = 0; n < 2; ++n) {
      const int tt = n * 16 + lh;
      const int ci = (o0 >> 3) ^ (tt & 7);
      const bf16x4 h4 = *(const bf16x4*)(ldsXC + tt * 256 + ci * 16 + (o0 & 7) * 2);
      f32x4 s4, xn;
      #pragma unroll
      for (int r = 0; r < 4; ++r) {
        s4[r] = acc2[n][r] + bo[r];
        xn[r] = s4[r] + b2f(h4[r]);
        __builtin_nontemporal_store(s4[r], skipBase + (size_t)(o0 + r) * NT + tt);
      }
      if (!last) {
        bf16x4 x4;
        #pragma unroll
        for (int r = 0; r < 4; ++r) x4[r] = f2b(xn[r]);
        *(bf16x4*)(ldsXC + tt * 256 + ci * 16 + (o0 & 7) * 2) = x4;
      } else {
        #pragma unroll
        for (int r = 0; r < 4; ++r)
          __builtin_nontemporal_store(xn[r], xBase + (size_t)(o0 + r) * NT + tt);
      }
    }
  }

  if (!last) {
    __syncthreads();
    // xb: full 256B rows (cached — re-read next layer)
    char* dstBase = (char*)xbout + ((size_t)(b * NT + t0)) * 256;
    *(f32x4*)(dstBase + tid * 16) = *(const f32x4*)(ldsXC + tid * 16);
  }
}

extern "C" void kernel_launch(void* const* d_in, const int* in_sizes, int n_in,
                              void* d_out, int out_size, void* d_ws, size_t ws_size,
                              hipStream_t stream) {
  const float* x      = (const float*)d_in[0];
  const float* w_conv = (const float*)d_in[1];
  const float* b_conv = (const float*)d_in[2];
  const float* w_out  = (const float*)d_in[3];
  const float* b_out  = (const float*)d_in[4];
  float* out = (float*)d_out;

  const size_t XTN = (size_t)NB * NT * NC;
  short* xb[2];
  xb[0] = (short*)d_ws;
  xb[1] = xb[0] + XTN;
  short* wcb = xb[1] + XTN;
  short* wob = wcb + CONVN;

  pack_weights<<<(CONVN + WOUTN + 255) / 256, 256, 0, stream>>>(w_conv, w_out, wcb, wob);
  transpose_in<<<dim3(NT / 64, NC / 64, NB), 256, 0, stream>>>(x, xb[0]);

  static const int dil[NLAYER] = {1, 2, 4, 8, 16, 32, 64, 128, 256, 512,
                                  1, 2, 4, 8, 16, 32, 64, 128, 256, 512};
  for (int i = 0; i < NLAYER; ++i) {
    wavenet_layer32<<<dim3(1024), 512, 0, stream>>>(
        wcb, b_conv, wob, b_out, xb[i & 1], xb[(i & 1) ^ 1], out, i, dil[i],
        (i == NLAYER - 1) ? 1 : 0);
  }
}